// Round 1
// baseline (477.132 us; speedup 1.0000x reference)
//
#include <hip/hip_runtime.h>
#include <hip/hip_bf16.h>

#define B_  8
#define T_  4096
#define D_  1024
#define M_  (B_*T_)   // 32768
#define N_  (2*D_)    // 2048
#define K_  D_        // 1024
#define NC_ 32        // chunks over T
#define C_  (T_/NC_)  // 128 steps per chunk

typedef short bf16x8 __attribute__((ext_vector_type(8)));
typedef float f32x4  __attribute__((ext_vector_type(4)));

__device__ __forceinline__ unsigned short f2bf(float f) {
  union { float f; unsigned int u; } v; v.f = f;
  unsigned int r = (v.u + 0x7fffu + ((v.u >> 16) & 1u)) >> 16;
  return (unsigned short)r;
}

__device__ __forceinline__ float bf2f(unsigned short u) {
  union { unsigned int u; float f; } v; v.u = ((unsigned int)u) << 16; return v.f;
}

__device__ __forceinline__ float sigm(float x) {
  return 1.0f / (1.0f + __expf(-x));
}

// async global->LDS, 16B per lane; lds base must be wave-uniform
__device__ __forceinline__ void async16(const void* g, void* l) {
  __builtin_amdgcn_global_load_lds((const __attribute__((address_space(1))) void*)g,
                                   (__attribute__((address_space(3))) void*)l,
                                   16, 0, 0);
}

// ---------------- cast kernels ----------------
__global__ void cast_x_kernel(const float* __restrict__ x, unsigned short* __restrict__ xb) {
  const long n4 = (long)M_ * K_ / 4;
  long i = (long)blockIdx.x * blockDim.x + threadIdx.x;
  const long stride = (long)gridDim.x * blockDim.x;
  for (; i < n4; i += stride) {
    float4 v = ((const float4*)x)[i];
    ushort4 o;
    o.x = f2bf(v.x); o.y = f2bf(v.y); o.z = f2bf(v.z); o.w = f2bf(v.w);
    ((ushort4*)xb)[i] = o;
  }
}

// W [K, N] fp32 -> Wt [N, K] bf16 (tiled transpose)
__global__ void cast_wt_kernel(const float* __restrict__ W, unsigned short* __restrict__ Wt) {
  __shared__ float tile[32][33];
  const int n0 = blockIdx.x * 32, k0 = blockIdx.y * 32;
  const int tx = threadIdx.x, ty = threadIdx.y; // (32, 8)
  for (int i = 0; i < 32; i += 8)
    tile[ty + i][tx] = W[(size_t)(k0 + ty + i) * N_ + n0 + tx];
  __syncthreads();
  for (int i = 0; i < 32; i += 8)
    Wt[(size_t)(n0 + ty + i) * K_ + k0 + tx] = f2bf(tile[tx][ty + i]);
}

// ---------------- GEMM: 256x256 tile, 8-phase counted-vmcnt schedule ----------------
// P = Xb @ Wt^T + bias, fused gate epilogue, bf16 out via LDS-transpose wide stores.
#define BM 256
#define BN 256
#define BK 64
#define NT (K_/BK)               // 16 K-tiles
#define LDSA(b) ((b)*32768)      // elem offset of A region of buffer b
#define LDSB(b) ((b)*32768 + 16384)

#define BARX()  __builtin_amdgcn_s_barrier()
#define LGKM0() asm volatile("s_waitcnt lgkmcnt(0)" ::: "memory")
#define SB0()   __builtin_amdgcn_sched_barrier(0)
#define VM8()   asm volatile("s_waitcnt vmcnt(8)" ::: "memory")
#define VM0()   asm volatile("s_waitcnt vmcnt(0)" ::: "memory")

// stage one 256x64 tile (A or B) of K-tile at elem col offset KOFF into buffer BUF.
// 4 rounds x (512 thr x 16B); wave-uniform LDS base, pre-swizzled global source.
#define STAGE_Bt(BUF, KOFF) do {                                                \
    _Pragma("unroll")                                                           \
    for (int r = 0; r < 4; ++r)                                                 \
      async16(aB + (KOFF) + r*64*K_, lds + LDSB(BUF) + w*512 + r*4096);         \
  } while (0)
#define STAGE_At(BUF, KOFF) do {                                                \
    _Pragma("unroll")                                                           \
    for (int r = 0; r < 4; ++r)                                                 \
      async16(aA + (KOFF) + r*64*K_, lds + LDSA(BUF) + w*512 + r*4096);         \
  } while (0)

#define RD_A(MBASE, BUF) do {                                                   \
    _Pragma("unroll")                                                           \
    for (int m = 0; m < 4; ++m) {                                               \
      af[m][0] = *(const bf16x8*)(lds + LDSA(BUF) + (rowA + (MBASE + m)*16)*64 + cc0); \
      af[m][1] = *(const bf16x8*)(lds + LDSA(BUF) + (rowA + (MBASE + m)*16)*64 + cc1); \
    } } while (0)
#define RD_B(NBASE, BUF) do {                                                   \
    _Pragma("unroll")                                                           \
    for (int n = 0; n < 2; ++n) {                                               \
      bfr[NBASE + n][0] = *(const bf16x8*)(lds + LDSB(BUF) + (rowB + (NBASE + n)*16)*64 + cc0); \
      bfr[NBASE + n][1] = *(const bf16x8*)(lds + LDSB(BUF) + (rowB + (NBASE + n)*16)*64 + cc1); \
    } } while (0)

#define MFMA_Q(MB, NB) do {                                                     \
    __builtin_amdgcn_s_setprio(1);                                              \
    _Pragma("unroll")                                                           \
    for (int m = 0; m < 4; ++m)                                                 \
      _Pragma("unroll")                                                         \
      for (int n = 0; n < 2; ++n) {                                             \
        acc[MB+m][NB+n] = __builtin_amdgcn_mfma_f32_16x16x32_bf16(af[m][0], bfr[NB+n][0], acc[MB+m][NB+n], 0, 0, 0); \
        acc[MB+m][NB+n] = __builtin_amdgcn_mfma_f32_16x16x32_bf16(af[m][1], bfr[NB+n][1], acc[MB+m][NB+n], 0, 0, 0); \
      }                                                                         \
    __builtin_amdgcn_s_setprio(0);                                              \
  } while (0)

// One K-tile = 4 phases. Staging of the next-next tile goes into THIS buffer:
// B-region free after P1's trailing barrier, A-region after P2's trailing barrier.
// VMW at P3-end: counted vmcnt(8) = just-issued 8 loads; everything older landed.
#define TILE(BUF, DO_STAGE, KOFF, VMW) do {                                     \
    /* P0 */                                                                    \
    RD_A(0, BUF); RD_B(0, BUF);                                                 \
    BARX(); LGKM0(); SB0();                                                     \
    MFMA_Q(0, 0);                                                               \
    BARX();                                                                     \
    /* P1 */                                                                    \
    RD_B(2, BUF);                                                               \
    BARX(); LGKM0(); SB0();                                                     \
    MFMA_Q(0, 2);                                                               \
    BARX();                                                                     \
    /* P2 */                                                                    \
    if (DO_STAGE) STAGE_Bt(BUF, KOFF);                                          \
    RD_A(4, BUF);                                                               \
    BARX(); LGKM0(); SB0();                                                     \
    MFMA_Q(4, 0);                                                               \
    BARX();                                                                     \
    /* P3 */                                                                    \
    if (DO_STAGE) STAGE_At(BUF, KOFF);                                          \
    MFMA_Q(4, 2);                                                               \
    VMW;                                                                        \
    BARX();                                                                     \
  } while (0)

__global__ __launch_bounds__(512, 2) void gemm_kernel(
    const unsigned short* __restrict__ A,
    const unsigned short* __restrict__ Bt,
    const float* __restrict__ bias,
    unsigned short* __restrict__ Sout,
    unsigned short* __restrict__ Gout) {
  __shared__ unsigned short lds[65536];   // 128 KB: 2 bufs x (A 16K + B 16K elems)

  const int tid  = threadIdx.x;
  const int w    = tid >> 6;      // wave 0..7
  const int lane = tid & 63;
  const int wm   = w >> 2;        // 0..1  (128 rows each)
  const int wn   = w & 3;         // 0..3  (64 cols each)
  const int quad = lane >> 4, n15 = lane & 15;

  // XCD-aware swizzle: all 8 n-blocks of an m-tile stay on one XCD, consecutive.
  const int bid   = blockIdx.x;          // 0..1023
  const int xcd   = bid & 7;
  const int j     = bid >> 3;            // 0..127
  const int n_idx = j & 7;
  const int m_idx = (j >> 3) * 8 + xcd;  // 0..127
  const int m0 = m_idx * BM, n0 = n_idx * BN;

  // staging lane geometry: lane covers row (w*8 + lr), 16B group lg, source
  // column group pre-swizzled by lg ^ (row&7) so LDS stays linear.
  const int lr = lane >> 3, lg = lane & 7;
  const int sg8 = (lg ^ lr) * 8;
  const unsigned short* aA = A  + (size_t)(m0 + w*8 + lr) * K_ + sg8;
  const unsigned short* aB = Bt + (size_t)(n0 + w*8 + lr) * K_ + sg8;

  // fragment-read offsets: row&7 == n15&7 for all fragment rows
  const int n7  = n15 & 7;
  const int cc0 = (quad ^ n7) * 8;   // k-slice 0
  const int cc1 = cc0 ^ 32;          // k-slice 1 (group ^ 4)
  const int rowA = wm * 128 + n15;
  const int rowB = wn * 64  + n15;

  f32x4 acc[8][4];
  #pragma unroll
  for (int i = 0; i < 8; ++i)
    #pragma unroll
    for (int jj = 0; jj < 4; ++jj) acc[i][jj] = (f32x4){0.f, 0.f, 0.f, 0.f};

  bf16x8 af[4][2], bfr[4][2];

  // prologue: tile0 -> buf0, tile1 -> buf1; wait for tile0 (8 newest stay in flight)
  STAGE_Bt(0, 0);  STAGE_At(0, 0);
  STAGE_Bt(1, 64); STAGE_At(1, 64);
  VM8();
  BARX();

  int koff = 128;   // k elem offset of next staged tile (tile 2)
  #pragma unroll 1
  for (int it = 0; it < 7; ++it) {
    TILE(0, 1, koff,      VM8());
    TILE(1, 1, koff + 64, VM8());
    koff += 128;
  }
  TILE(0, 0, 0, VM0());     // tile 14; drain so tile 15 is landed
  TILE(1, 0, 0, ((void)0)); // tile 15

  // ---- epilogue: bias + gate, LDS transpose (XOR-swizzled), wide stores ----
  const bool is_k = (n0 >= D_);
  unsigned short* __restrict__ dst = is_k ? Sout : Gout;
  const int d0 = is_k ? (n0 - D_) : n0;
  float bv[4];
  #pragma unroll
  for (int jj = 0; jj < 4; ++jj) bv[jj] = bias[n0 + wn*64 + jj*16 + n15];

  #pragma unroll
  for (int i = 0; i < 8; ++i) {
    #pragma unroll
    for (int jj = 0; jj < 4; ++jj) {
      const int col = wn*64 + jj*16 + n15;          // block-local col
      #pragma unroll
      for (int r = 0; r < 4; ++r) {
        const int row = wm*128 + i*16 + quad*4 + r; // block-local row
        const float val = acc[i][jj][r] + bv[jj];
        const float o = is_k ? sigm(val)
                             : ((val >= 0.0f) ? (val + 0.5f) : sigm(val));
        const int slot = (col >> 3) ^ (row & 7);    // 8-elem-group XOR swizzle
        lds[row*256 + slot*8 + (col & 7)] = f2bf(o);
      }
    }
  }
  __syncthreads();
  const int trow = tid >> 5;   // 0..15
  const int cg   = tid & 31;   // 16B group within row
  #pragma unroll
  for (int rr = 0; rr < 16; ++rr) {
    const int row = rr*16 + trow;
    const uint4 v = *(const uint4*)(lds + row*256 + ((cg ^ (row & 7)) * 8));
    *(uint4*)(dst + (size_t)(m0 + row) * D_ + d0 + cg*8) = v;
  }
}

// ---------------- pass 1: per-chunk aggregates ----------------
__global__ void chunk_agg_kernel(const unsigned short* __restrict__ S,
                                 const unsigned short* __restrict__ G,
                                 float* __restrict__ AggA, float* __restrict__ AggV) {
  const int d = blockIdx.x * 256 + threadIdx.x;
  const int c = blockIdx.y;
  const int b = blockIdx.z;
  size_t base = ((size_t)b * T_ + (size_t)c * C_) * D_ + d;
  float Aa = 1.0f, V = 0.0f;
  for (int t = 0; t < C_; ++t) {
    const float s = bf2f(S[base]);
    const float g = bf2f(G[base]);
    const float a = 1.0f - s;
    V = fmaf(a, V, s * g);
    Aa *= a;
    base += D_;
  }
  const int idx = (b * NC_ + c) * D_ + d;
  AggA[idx] = Aa;
  AggV[idx] = V;
}

// ---------------- pass 2: exclusive scan over chunk aggregates ----------------
__global__ void chunk_scan_kernel(const float* __restrict__ AggA, const float* __restrict__ AggV,
                                  float* __restrict__ H0) {
  const int d = blockIdx.x * 256 + threadIdx.x;
  const int b = blockIdx.y;
  float h = 0.0f;
  for (int c = 0; c < NC_; ++c) {
    const int idx = (b * NC_ + c) * D_ + d;
    H0[idx] = h;
    h = fmaf(AggA[idx], h, AggV[idx]);
  }
}

// ---------------- pass 3: replay scan + residual + LayerNorm, phase-swapped ----------------
__global__ __launch_bounds__(1024, 1) void scan_ln_kernel(
    const unsigned short* __restrict__ S, const unsigned short* __restrict__ G,
    const float* __restrict__ x, const float* __restrict__ H0,
    const float* __restrict__ gamma, const float* __restrict__ beta,
    float* __restrict__ out) {
  __shared__ float yb[16 * 1024];
  const int d = threadIdx.x;         // 0..1023
  const int c = blockIdx.x;
  const int b = blockIdx.y;
  const int wid = d >> 6, lane = d & 63;

  float h = H0[(b * NC_ + c) * D_ + d];
  float gam[16], bet[16];
  for (int j = 0; j < 16; ++j) { gam[j] = gamma[lane + 64 * j]; bet[j] = beta[lane + 64 * j]; }

  size_t base = ((size_t)b * T_ + (size_t)c * C_) * D_ + d;
  for (int batch = 0; batch < 8; ++batch) {
    for (int tt = 0; tt < 16; ++tt) {
      const size_t idx = base + (size_t)tt * D_;
      const float s = bf2f(S[idx]);
      const float g = bf2f(G[idx]);
      h = fmaf(s, g - h, h);           // (1-s)*h + s*g
      yb[tt * 1024 + d] = x[idx] + h;
    }
    __syncthreads();
    {
      float sy = 0.0f, sq = 0.0f;
      float yv[16];
      for (int j = 0; j < 16; ++j) {
        const float v = yb[wid * 1024 + lane + 64 * j];
        yv[j] = v; sy += v; sq += v * v;
      }
      for (int o = 32; o > 0; o >>= 1) {
        sy += __shfl_down(sy, o);
        sq += __shfl_down(sq, o);
      }
      sy = __shfl(sy, 0); sq = __shfl(sq, 0);
      const float mu   = sy * (1.0f / D_);
      const float rstd = rsqrtf(sq * (1.0f / D_) - mu * mu + 1e-6f);
      const size_t obase = ((size_t)b * T_ + (size_t)c * C_ + (size_t)batch * 16 + wid) * D_;
      for (int j = 0; j < 16; ++j)
        out[obase + lane + 64 * j] = (yv[j] - mu) * rstd * gam[j] + bet[j];
    }
    __syncthreads();
    base += (size_t)16 * D_;
  }
}

// ---------------- launcher ----------------
extern "C" void kernel_launch(void* const* d_in, const int* in_sizes, int n_in,
                              void* d_out, int out_size, void* d_ws, size_t ws_size,
                              hipStream_t stream) {
  const float* x     = (const float*)d_in[0];
  const float* W     = (const float*)d_in[1];
  const float* bias  = (const float*)d_in[2];
  const float* gamma = (const float*)d_in[3];
  const float* beta  = (const float*)d_in[4];
  float* out = (float*)d_out;

  char* ws = (char*)d_ws;
  unsigned short* Wt = (unsigned short*)ws;  ws += (size_t)N_ * K_ * 2;        // 4 MB
  unsigned short* Xb = (unsigned short*)ws;  ws += (size_t)M_ * K_ * 2;        // 64 MB
  unsigned short* S  = (unsigned short*)ws;  ws += (size_t)M_ * D_ * 2;        // 64 MB
  unsigned short* G  = (unsigned short*)ws;  ws += (size_t)M_ * D_ * 2;        // 64 MB
  float* AggA = (float*)ws;                  ws += (size_t)B_ * NC_ * D_ * 4;  // 1 MB
  float* AggV = (float*)ws;                  ws += (size_t)B_ * NC_ * D_ * 4;  // 1 MB
  float* H0   = (float*)ws;                  ws += (size_t)B_ * NC_ * D_ * 4;  // 1 MB

  cast_x_kernel<<<4096, 256, 0, stream>>>(x, Xb);
  cast_wt_kernel<<<dim3(N_ / 32, K_ / 32), dim3(32, 8), 0, stream>>>(W, Wt);
  gemm_kernel<<<1024, 512, 0, stream>>>(Xb, Wt, bias, S, G);
  chunk_agg_kernel<<<dim3(D_ / 256, NC_, B_), 256, 0, stream>>>(S, G, AggA, AggV);
  chunk_scan_kernel<<<dim3(D_ / 256, B_), 256, 0, stream>>>(AggA, AggV, H0);
  scan_ln_kernel<<<dim3(NC_, B_), 1024, 0, stream>>>(S, G, x, H0, gamma, beta, out);
}

// Round 2
// 475.618 us; speedup vs baseline: 1.0032x; 1.0032x over previous
//
#include <hip/hip_runtime.h>
#include <hip/hip_bf16.h>

#define B_  8
#define T_  4096
#define D_  1024
#define M_  (B_*T_)   // 32768
#define N_  (2*D_)    // 2048
#define K_  D_        // 1024
#define NC_ 32        // chunks over T
#define C_  (T_/NC_)  // 128 steps per chunk

typedef short bf16x8 __attribute__((ext_vector_type(8)));
typedef float f32x4  __attribute__((ext_vector_type(4)));

__device__ __forceinline__ unsigned short f2bf(float f) {
  union { float f; unsigned int u; } v; v.f = f;
  unsigned int r = (v.u + 0x7fffu + ((v.u >> 16) & 1u)) >> 16;
  return (unsigned short)r;
}

__device__ __forceinline__ float bf2f(unsigned short u) {
  union { unsigned int u; float f; } v; v.u = ((unsigned int)u) << 16; return v.f;
}

__device__ __forceinline__ float sigm(float x) {
  return 1.0f / (1.0f + __expf(-x));
}

// async global->LDS, 16B per lane; lds base must be wave-uniform
__device__ __forceinline__ void async16(const void* g, void* l) {
  __builtin_amdgcn_global_load_lds((const __attribute__((address_space(1))) void*)g,
                                   (__attribute__((address_space(3))) void*)l,
                                   16, 0, 0);
}

// ---------------- cast kernels ----------------
__global__ void cast_x_kernel(const float* __restrict__ x, unsigned short* __restrict__ xb) {
  const long n4 = (long)M_ * K_ / 4;
  long i = (long)blockIdx.x * blockDim.x + threadIdx.x;
  const long stride = (long)gridDim.x * blockDim.x;
  for (; i < n4; i += stride) {
    float4 v = ((const float4*)x)[i];
    ushort4 o;
    o.x = f2bf(v.x); o.y = f2bf(v.y); o.z = f2bf(v.z); o.w = f2bf(v.w);
    ((ushort4*)xb)[i] = o;
  }
}

// W [K, N] fp32 -> Wt [N, K] bf16 (tiled transpose)
__global__ void cast_wt_kernel(const float* __restrict__ W, unsigned short* __restrict__ Wt) {
  __shared__ float tile[32][33];
  const int n0 = blockIdx.x * 32, k0 = blockIdx.y * 32;
  const int tx = threadIdx.x, ty = threadIdx.y; // (32, 8)
  for (int i = 0; i < 32; i += 8)
    tile[ty + i][tx] = W[(size_t)(k0 + ty + i) * N_ + n0 + tx];
  __syncthreads();
  for (int i = 0; i < 32; i += 8)
    Wt[(size_t)(n0 + ty + i) * K_ + k0 + tx] = f2bf(tile[tx][ty + i]);
}

// ---------------- GEMM: 256x256 tile, per-wave pipelined, 1 barrier/K-tile ----
// P = Xb @ Wt^T + bias, fused gate epilogue, bf16 out via LDS-transpose stores.
#define BM 256
#define BN 256
#define BK 64
#define LDSA(b) ((b)*32768)      // elem offset of A region of buffer b
#define LDSB(b) ((b)*32768 + 16384)

#define SB0()   __builtin_amdgcn_sched_barrier(0)
#define VM0()   asm volatile("s_waitcnt vmcnt(0)" ::: "memory")

// stage one 256x64 tile (A or B) of the K-tile at elem col KOFF into buffer BUF.
// 4 rounds x (512 thr x 16B); wave-uniform LDS base, pre-swizzled global source.
#define STAGE_Bt(BUF, KOFF) do {                                                \
    _Pragma("unroll")                                                           \
    for (int r = 0; r < 4; ++r)                                                 \
      async16(aB + (KOFF) + r*64*K_, lds + LDSB(BUF) + w*512 + r*4096);         \
  } while (0)
#define STAGE_At(BUF, KOFF) do {                                                \
    _Pragma("unroll")                                                           \
    for (int r = 0; r < 4; ++r)                                                 \
      async16(aA + (KOFF) + r*64*K_, lds + LDSA(BUF) + w*512 + r*4096);         \
  } while (0)

// 8 ds_read_b128 into afA: A rows (rowA + (MBASE..MBASE+3)*16), both k-slices
#define RD_A8(MBASE, BUF) do {                                                  \
    _Pragma("unroll")                                                           \
    for (int m = 0; m < 4; ++m) {                                               \
      afA[m][0] = *(const bf16x8*)(lds + LDSA(BUF) + (rowA + (MBASE + m)*16)*64 + cc0); \
      afA[m][1] = *(const bf16x8*)(lds + LDSA(BUF) + (rowA + (MBASE + m)*16)*64 + cc1); \
    } } while (0)
// 4 ds_read_b128 into ARR: B rows (rowB + (NBASE..NBASE+1)*16)
#define RD_B4(ARR, NBASE, BUF) do {                                             \
    _Pragma("unroll")                                                           \
    for (int n = 0; n < 2; ++n) {                                               \
      ARR[n][0] = *(const bf16x8*)(lds + LDSB(BUF) + (rowB + (NBASE + n)*16)*64 + cc0); \
      ARR[n][1] = *(const bf16x8*)(lds + LDSB(BUF) + (rowB + (NBASE + n)*16)*64 + cc1); \
    } } while (0)

// one C-quadrant x K=64: 16 MFMA using afA x BARR
#define MQ(BARR, MB, NB) do {                                                   \
    __builtin_amdgcn_s_setprio(1);                                              \
    _Pragma("unroll")                                                           \
    for (int m = 0; m < 4; ++m)                                                 \
      _Pragma("unroll")                                                         \
      for (int n = 0; n < 2; ++n) {                                             \
        acc[MB+m][NB+n] = __builtin_amdgcn_mfma_f32_16x16x32_bf16(afA[m][0], BARR[n][0], acc[MB+m][NB+n], 0, 0, 0); \
        acc[MB+m][NB+n] = __builtin_amdgcn_mfma_f32_16x16x32_bf16(afA[m][1], BARR[n][1], acc[MB+m][NB+n], 0, 0, 0); \
      }                                                                         \
    __builtin_amdgcn_s_setprio(0);                                              \
  } while (0)

// One K-tile, reading buffer BR, staging the NEXT tile (KOFF) into BW.
// Dep-driven overlap: 16 ds_reads + 8 stage loads issued up front; compiler
// inserts counted lgkmcnt per consumer (B1 flies under Q00; stage loads have
// the whole tile to land). A rows 64-127 reload into afA mid-tile (WAR handled
// by regalloc); single vmcnt(0)+barrier per tile — drains loads issued a full
// tile earlier (free), unlike the per-phase lockstep which serialized LDS+MFMA.
#define TILE_V2(BR, BW, DO_STAGE, KOFF) do {                                    \
    RD_A8(0, BR);                         /* afA  <- A rows 0-63  */            \
    RD_B4(bfrA, 0, BR);                   /* B0   <- cols 0-31    */            \
    RD_B4(bfrB, 2, BR);                   /* B1   <- cols 32-63   */            \
    if (DO_STAGE) { STAGE_Bt(BW, KOFF); STAGE_At(BW, KOFF); SB0(); }            \
    MQ(bfrA, 0, 0);                       /* Q00 (A0,B0) */                     \
    MQ(bfrB, 0, 2);                       /* Q02 (A0,B1) */                     \
    RD_A8(4, BR);                         /* afA  <- A rows 64-127 */           \
    MQ(bfrB, 4, 2);                       /* Q42 (A1,B1) */                     \
    MQ(bfrA, 4, 0);                       /* Q40 (A1,B0) */                     \
    VM0();                                                                      \
    __syncthreads();                                                            \
  } while (0)

__global__ __launch_bounds__(512, 2) void gemm_kernel(
    const unsigned short* __restrict__ A,
    const unsigned short* __restrict__ Bt,
    const float* __restrict__ bias,
    unsigned short* __restrict__ Sout,
    unsigned short* __restrict__ Gout) {
  __shared__ unsigned short lds[65536];   // 128 KB: 2 bufs x (A 16K + B 16K elems)

  const int tid  = threadIdx.x;
  const int w    = tid >> 6;      // wave 0..7
  const int lane = tid & 63;
  const int wm   = w >> 2;        // 0..1  (128 rows each)
  const int wn   = w & 3;         // 0..3  (64 cols each)
  const int quad = lane >> 4, n15 = lane & 15;

  // XCD-aware swizzle: all 8 n-blocks of an m-tile stay on one XCD, consecutive.
  const int bid   = blockIdx.x;          // 0..1023
  const int xcd   = bid & 7;
  const int j     = bid >> 3;            // 0..127
  const int n_idx = j & 7;
  const int m_idx = (j >> 3) * 8 + xcd;  // 0..127
  const int m0 = m_idx * BM, n0 = n_idx * BN;

  // staging lane geometry: lane covers row (w*8 + lr), 16B group lg, source
  // column group pre-swizzled by lg ^ (row&7) so LDS stays linear.
  const int lr = lane >> 3, lg = lane & 7;
  const int sg8 = (lg ^ lr) * 8;
  const unsigned short* aA = A  + (size_t)(m0 + w*8 + lr) * K_ + sg8;
  const unsigned short* aB = Bt + (size_t)(n0 + w*8 + lr) * K_ + sg8;

  // fragment-read offsets: row&7 == n15&7 for all fragment rows
  const int n7  = n15 & 7;
  const int cc0 = (quad ^ n7) * 8;   // k-slice 0
  const int cc1 = cc0 ^ 32;          // k-slice 1 (group ^ 4)
  const int rowA = wm * 128 + n15;
  const int rowB = wn * 64  + n15;

  f32x4 acc[8][4];
  #pragma unroll
  for (int i = 0; i < 8; ++i)
    #pragma unroll
    for (int jj = 0; jj < 4; ++jj) acc[i][jj] = (f32x4){0.f, 0.f, 0.f, 0.f};

  bf16x8 afA[4][2], bfrA[2][2], bfrB[2][2];

  // prologue: tile0 -> buf0; drain + barrier
  STAGE_Bt(0, 0);  STAGE_At(0, 0);
  VM0();
  __syncthreads();

  int koff = 64;   // k elem offset of the next tile to stage
  #pragma unroll 1
  for (int it = 0; it < 7; ++it) {
    TILE_V2(0, 1, 1, koff);        // even tile: read buf0, stage -> buf1
    TILE_V2(1, 0, 1, koff + 64);   // odd tile:  read buf1, stage -> buf0
    koff += 128;
  }
  TILE_V2(0, 1, 1, koff);          // tile 14: read buf0, stage tile15 -> buf1
  TILE_V2(1, 0, 0, 0);             // tile 15: read buf1, no stage

  // ---- epilogue: bias + gate, LDS transpose (XOR-swizzled), wide stores ----
  const bool is_k = (n0 >= D_);
  unsigned short* __restrict__ dst = is_k ? Sout : Gout;
  const int d0 = is_k ? (n0 - D_) : n0;
  float bv[4];
  #pragma unroll
  for (int jj = 0; jj < 4; ++jj) bv[jj] = bias[n0 + wn*64 + jj*16 + n15];

  #pragma unroll
  for (int i = 0; i < 8; ++i) {
    #pragma unroll
    for (int jj = 0; jj < 4; ++jj) {
      const int col = wn*64 + jj*16 + n15;          // block-local col
      #pragma unroll
      for (int r = 0; r < 4; ++r) {
        const int row = wm*128 + i*16 + quad*4 + r; // block-local row
        const float val = acc[i][jj][r] + bv[jj];
        const float o = is_k ? sigm(val)
                             : ((val >= 0.0f) ? (val + 0.5f) : sigm(val));
        const int slot = (col >> 3) ^ (row & 7);    // 8-elem-group XOR swizzle
        lds[row*256 + slot*8 + (col & 7)] = f2bf(o);
      }
    }
  }
  __syncthreads();
  const int trow = tid >> 5;   // 0..15
  const int cg   = tid & 31;   // 16B group within row
  #pragma unroll
  for (int rr = 0; rr < 16; ++rr) {
    const int row = rr*16 + trow;
    const uint4 v = *(const uint4*)(lds + row*256 + ((cg ^ (row & 7)) * 8));
    *(uint4*)(dst + (size_t)(m0 + row) * D_ + d0 + cg*8) = v;
  }
}

// ---------------- pass 1: per-chunk aggregates ----------------
__global__ void chunk_agg_kernel(const unsigned short* __restrict__ S,
                                 const unsigned short* __restrict__ G,
                                 float* __restrict__ AggA, float* __restrict__ AggV) {
  const int d = blockIdx.x * 256 + threadIdx.x;
  const int c = blockIdx.y;
  const int b = blockIdx.z;
  size_t base = ((size_t)b * T_ + (size_t)c * C_) * D_ + d;
  float Aa = 1.0f, V = 0.0f;
  for (int t = 0; t < C_; ++t) {
    const float s = bf2f(S[base]);
    const float g = bf2f(G[base]);
    const float a = 1.0f - s;
    V = fmaf(a, V, s * g);
    Aa *= a;
    base += D_;
  }
  const int idx = (b * NC_ + c) * D_ + d;
  AggA[idx] = Aa;
  AggV[idx] = V;
}

// ---------------- pass 2: exclusive scan over chunk aggregates ----------------
__global__ void chunk_scan_kernel(const float* __restrict__ AggA, const float* __restrict__ AggV,
                                  float* __restrict__ H0) {
  const int d = blockIdx.x * 256 + threadIdx.x;
  const int b = blockIdx.y;
  float h = 0.0f;
  for (int c = 0; c < NC_; ++c) {
    const int idx = (b * NC_ + c) * D_ + d;
    H0[idx] = h;
    h = fmaf(AggA[idx], h, AggV[idx]);
  }
}

// ---------------- pass 3: replay scan + residual + LayerNorm, phase-swapped ----
__global__ __launch_bounds__(1024, 1) void scan_ln_kernel(
    const unsigned short* __restrict__ S, const unsigned short* __restrict__ G,
    const float* __restrict__ x, const float* __restrict__ H0,
    const float* __restrict__ gamma, const float* __restrict__ beta,
    float* __restrict__ out) {
  __shared__ float yb[16 * 1024];
  const int d = threadIdx.x;         // 0..1023
  const int c = blockIdx.x;
  const int b = blockIdx.y;
  const int wid = d >> 6, lane = d & 63;

  float h = H0[(b * NC_ + c) * D_ + d];
  float gam[16], bet[16];
  for (int j = 0; j < 16; ++j) { gam[j] = gamma[lane + 64 * j]; bet[j] = beta[lane + 64 * j]; }

  size_t base = ((size_t)b * T_ + (size_t)c * C_) * D_ + d;
  for (int batch = 0; batch < 8; ++batch) {
    for (int tt = 0; tt < 16; ++tt) {
      const size_t idx = base + (size_t)tt * D_;
      const float s = bf2f(S[idx]);
      const float g = bf2f(G[idx]);
      h = fmaf(s, g - h, h);           // (1-s)*h + s*g
      yb[tt * 1024 + d] = x[idx] + h;
    }
    __syncthreads();
    {
      float sy = 0.0f, sq = 0.0f;
      float yv[16];
      for (int j = 0; j < 16; ++j) {
        const float v = yb[wid * 1024 + lane + 64 * j];
        yv[j] = v; sy += v; sq += v * v;
      }
      for (int o = 32; o > 0; o >>= 1) {
        sy += __shfl_down(sy, o);
        sq += __shfl_down(sq, o);
      }
      sy = __shfl(sy, 0); sq = __shfl(sq, 0);
      const float mu   = sy * (1.0f / D_);
      const float rstd = rsqrtf(sq * (1.0f / D_) - mu * mu + 1e-6f);
      const size_t obase = ((size_t)b * T_ + (size_t)c * C_ + (size_t)batch * 16 + wid) * D_;
      for (int j = 0; j < 16; ++j)
        out[obase + lane + 64 * j] = (yv[j] - mu) * rstd * gam[j] + bet[j];
    }
    __syncthreads();
    base += (size_t)16 * D_;
  }
}

// ---------------- launcher ----------------
extern "C" void kernel_launch(void* const* d_in, const int* in_sizes, int n_in,
                              void* d_out, int out_size, void* d_ws, size_t ws_size,
                              hipStream_t stream) {
  const float* x     = (const float*)d_in[0];
  const float* W     = (const float*)d_in[1];
  const float* bias  = (const float*)d_in[2];
  const float* gamma = (const float*)d_in[3];
  const float* beta  = (const float*)d_in[4];
  float* out = (float*)d_out;

  char* ws = (char*)d_ws;
  unsigned short* Wt = (unsigned short*)ws;  ws += (size_t)N_ * K_ * 2;        // 4 MB
  unsigned short* Xb = (unsigned short*)ws;  ws += (size_t)M_ * K_ * 2;        // 64 MB
  unsigned short* S  = (unsigned short*)ws;  ws += (size_t)M_ * D_ * 2;        // 64 MB
  unsigned short* G  = (unsigned short*)ws;  ws += (size_t)M_ * D_ * 2;        // 64 MB
  float* AggA = (float*)ws;                  ws += (size_t)B_ * NC_ * D_ * 4;  // 1 MB
  float* AggV = (float*)ws;                  ws += (size_t)B_ * NC_ * D_ * 4;  // 1 MB
  float* H0   = (float*)ws;                  ws += (size_t)B_ * NC_ * D_ * 4;  // 1 MB

  cast_x_kernel<<<4096, 256, 0, stream>>>(x, Xb);
  cast_wt_kernel<<<dim3(N_ / 32, K_ / 32), dim3(32, 8), 0, stream>>>(W, Wt);
  gemm_kernel<<<1024, 512, 0, stream>>>(Xb, Wt, bias, S, G);
  chunk_agg_kernel<<<dim3(D_ / 256, NC_, B_), 256, 0, stream>>>(S, G, AggA, AggV);
  chunk_scan_kernel<<<dim3(D_ / 256, B_), 256, 0, stream>>>(AggA, AggV, H0);
  scan_ln_kernel<<<dim3(NC_, B_), 1024, 0, stream>>>(S, G, x, H0, gamma, beta, out);
}